// Round 1
// baseline (395.625 us; speedup 1.0000x reference)
//
#include <hip/hip_runtime.h>
#include <hip/hip_bf16.h>
#include <stdint.h>

#define HEADS 8
#define DHEAD 64
#define BATCH 4
#define SEQ   8192
#define DIM   256
#define INNER 512
#define QKVC  1536
#define ROWS  32768   // BATCH*SEQ
#define EPS   1e-5f

typedef unsigned short u16;
typedef __attribute__((ext_vector_type(8))) short bf16x8;
typedef __attribute__((ext_vector_type(4))) float f32x4;

#define AS1 __attribute__((address_space(1)))
#define AS3 __attribute__((address_space(3)))

__device__ __forceinline__ void async16(const void* g, void* l) {
  __builtin_amdgcn_global_load_lds((AS1 unsigned int*)g, (AS3 unsigned int*)l, 16, 0, 0);
}

__device__ __forceinline__ float bf2f(u16 u) {
  union { uint32_t i; float f; } v; v.i = ((uint32_t)u) << 16; return v.f;
}
__device__ __forceinline__ u16 f2bf(float f) {
  union { float f; uint32_t i; } v; v.f = f;
  uint32_t x = v.i;
  return (u16)((x + 0x7fffu + ((x >> 16) & 1u)) >> 16);  // RNE
}

// ---------------- conversion kernels ----------------
__global__ void cvt_x(const float* __restrict__ x, u16* __restrict__ xb, int n) {
  int i = (blockIdx.x * blockDim.x + threadIdx.x) * 4;
  if (i < n) {
    float4 v = *(const float4*)(x + i);
    u16 o0 = f2bf(v.x), o1 = f2bf(v.y), o2 = f2bf(v.z), o3 = f2bf(v.w);
    ushort4 o; o.x = o0; o.y = o1; o.z = o2; o.w = o3;
    *(ushort4*)(xb + i) = o;
  }
}

// w_qkv [256,1536] fp32 -> wT [1536,256] bf16
__global__ void cvt_wqkvT(const float* __restrict__ w, u16* __restrict__ wt) {
  int id = blockIdx.x * blockDim.x + threadIdx.x;  // 0..393215
  int n = id >> 8;     // 0..1535
  int k = id & 255;    // 0..255
  wt[id] = f2bf(w[k * QKVC + n]);
}

// ---------------- shared GEMM tile core (C = A @ Bt^T), 128x128 tile, BK=64 ----------------
__device__ __forceinline__ void gemm_tile(const u16* __restrict__ A, int lda,
                                          const u16* __restrict__ Bt, int ldb,
                                          int K, int row0, int col0,
                                          u16* sA, u16* sB, f32x4 acc[4][4]) {
  const int tid = threadIdx.x, lane = tid & 63, wave = tid >> 6;
  const int mr = (wave >> 1) * 64, nc = (wave & 1) * 64;
  for (int kk = 0; kk < K; kk += 64) {
#pragma unroll
    for (int it = 0; it < 4; ++it) {
      int s = it * 256 + tid;
      int r = s >> 3, c = (s & 7) << 3;
      // LDS dest: wave-uniform base; HW adds lane*16
      async16(A + (size_t)(row0 + r) * lda + kk + c, sA + (it * 256 + wave * 64) * 8);
      async16(Bt + (size_t)(col0 + r) * ldb + kk + c, sB + (it * 256 + wave * 64) * 8);
    }
    __syncthreads();
#pragma unroll
    for (int ks = 0; ks < 2; ++ks) {
      bf16x8 af[4], bfr[4];
#pragma unroll
      for (int f = 0; f < 4; ++f) {
        af[f]  = *(const bf16x8*)&sA[(mr + f * 16 + (lane & 15)) * 64 + ks * 32 + (lane >> 4) * 8];
        bfr[f] = *(const bf16x8*)&sB[(nc + f * 16 + (lane & 15)) * 64 + ks * 32 + (lane >> 4) * 8];
      }
#pragma unroll
      for (int fm = 0; fm < 4; ++fm)
#pragma unroll
        for (int fn = 0; fn < 4; ++fn)
          acc[fm][fn] = __builtin_amdgcn_mfma_f32_16x16x32_bf16(af[fm], bfr[fn], acc[fm][fn], 0, 0, 0);
    }
    __syncthreads();
  }
}

// GEMM1: qkv = x @ w_qkv ; A=[32768,256] bf16, Bt=[1536,256] bf16, C bf16 [32768,1536]
__global__ __launch_bounds__(256) void gemm1(const u16* __restrict__ A,
                                             const u16* __restrict__ Bt,
                                             u16* __restrict__ C) {
  __shared__ alignas(16) u16 sA[128 * 64];
  __shared__ alignas(16) u16 sB[128 * 64];
  const int lane = threadIdx.x & 63, wave = threadIdx.x >> 6;
  const int row0 = blockIdx.x * 128, col0 = blockIdx.y * 128;
  f32x4 acc[4][4];
#pragma unroll
  for (int i = 0; i < 4; ++i)
#pragma unroll
    for (int j = 0; j < 4; ++j) acc[i][j] = (f32x4){0.f, 0.f, 0.f, 0.f};

  gemm_tile(A, DIM, Bt, DIM, DIM, row0, col0, sA, sB, acc);

  const int mr = (wave >> 1) * 64, nc = (wave & 1) * 64;
#pragma unroll
  for (int fm = 0; fm < 4; ++fm) {
    int rbase = row0 + mr + fm * 16 + (lane >> 4) * 4;
#pragma unroll
    for (int fn = 0; fn < 4; ++fn) {
      int col = col0 + nc + fn * 16 + (lane & 15);
#pragma unroll
      for (int r = 0; r < 4; ++r)
        C[(size_t)(rbase + r) * QKVC + col] = f2bf(acc[fm][fn][r]);
    }
  }
}

// GEMM2: out[b] = q[b] @ Mbt[b]^T + bias ; A = qkv (first 512 cols), Bt = Mbt[b] [256,512]
__global__ __launch_bounds__(256) void gemm2(const u16* __restrict__ A,
                                             const u16* __restrict__ Mbt,
                                             const float* __restrict__ bias,
                                             float* __restrict__ out) {
  __shared__ alignas(16) u16 sA[128 * 64];
  __shared__ alignas(16) u16 sB[128 * 64];
  const int lane = threadIdx.x & 63, wave = threadIdx.x >> 6;
  const int row0 = blockIdx.x * 128, col0 = blockIdx.y * 128;
  const int b = blockIdx.x >> 6;  // 8192/128 = 64 row-blocks per batch
  const u16* BtB = Mbt + (size_t)b * 256 * 512;
  f32x4 acc[4][4];
#pragma unroll
  for (int i = 0; i < 4; ++i)
#pragma unroll
    for (int j = 0; j < 4; ++j) acc[i][j] = (f32x4){0.f, 0.f, 0.f, 0.f};

  gemm_tile(A, QKVC, BtB, INNER, INNER, row0, col0, sA, sB, acc);

  const int mr = (wave >> 1) * 64, nc = (wave & 1) * 64;
#pragma unroll
  for (int fm = 0; fm < 4; ++fm) {
    int rbase = row0 + mr + fm * 16 + (lane >> 4) * 4;
#pragma unroll
    for (int fn = 0; fn < 4; ++fn) {
      int col = col0 + nc + fn * 16 + (lane & 15);
      float bb = bias[col];
#pragma unroll
      for (int r = 0; r < 4; ++r)
        out[(size_t)(rbase + r) * DIM + col] = acc[fm][fn][r] + bb;
    }
  }
}

// ---------------- instance-norm + dots reduction ----------------
// grid (32 = b*h, 8 chunks of 1024 tokens), block 256
__global__ __launch_bounds__(256) void norm_dots(const u16* __restrict__ qkv,
                                                 float* __restrict__ dots) {
  __shared__ alignas(16) u16 knT[64 * 136];
  __shared__ alignas(16) u16 vnT[64 * 136];
  const int bh = blockIdx.x, b = bh >> 3, h = bh & 7;
  const int tid = threadIdx.x, lane = tid & 63, wave = tid >> 6;
  const int nbase = blockIdx.y * 1024;

  f32x4 acc[4];
#pragma unroll
  for (int f = 0; f < 4; ++f) acc[f] = (f32x4){0.f, 0.f, 0.f, 0.f};

  for (int tile = 0; tile < 8; ++tile) {
    // phase 1: wave-per-token instance norm, write transposed bf16 to LDS
    for (int t8 = 0; t8 < 32; ++t8) {
      int tok = t8 * 4 + wave;
      int row = b * SEQ + nbase + tile * 128 + tok;
      const u16* p = qkv + (size_t)row * QKVC + 512 + h * 64;
      float kv = bf2f(p[lane]);
      float vv = bf2f(p[512 + lane]);
      float sk = kv, sk2 = kv * kv, sv = vv, sv2 = vv * vv;
#pragma unroll
      for (int off = 32; off; off >>= 1) {
        sk  += __shfl_xor(sk, off, 64);
        sk2 += __shfl_xor(sk2, off, 64);
        sv  += __shfl_xor(sv, off, 64);
        sv2 += __shfl_xor(sv2, off, 64);
      }
      float muk = sk * (1.f / 64.f), vark = sk2 * (1.f / 64.f) - muk * muk;
      float muv = sv * (1.f / 64.f), varv = sv2 * (1.f / 64.f) - muv * muv;
      float rsk = rsqrtf(vark + EPS), rsv = rsqrtf(varv + EPS);
      knT[lane * 136 + tok] = f2bf((kv - muk) * rsk);
      vnT[lane * 136 + tok] = f2bf((vv - muv) * rsv);
    }
    __syncthreads();
    // phase 2: dots[d][e] += sum_tok knT[d][tok]*vnT[e][tok] via MFMA (K=128 tokens)
#pragma unroll
    for (int ks = 0; ks < 4; ++ks) {
      bf16x8 a = *(const bf16x8*)&knT[(wave * 16 + (lane & 15)) * 136 + ks * 32 + (lane >> 4) * 8];
#pragma unroll
      for (int fn = 0; fn < 4; ++fn) {
        bf16x8 bb = *(const bf16x8*)&vnT[(fn * 16 + (lane & 15)) * 136 + ks * 32 + (lane >> 4) * 8];
        acc[fn] = __builtin_amdgcn_mfma_f32_16x16x32_bf16(a, bb, acc[fn], 0, 0, 0);
      }
    }
    __syncthreads();
  }

  float* dbase = dots + (size_t)bh * 4096;
#pragma unroll
  for (int fn = 0; fn < 4; ++fn) {
    int e = fn * 16 + (lane & 15);
#pragma unroll
    for (int r = 0; r < 4; ++r) {
      int d = wave * 16 + (lane >> 4) * 4 + r;
      atomicAdd(dbase + d * 64 + e, acc[fn][r]);
    }
  }
}

// ---------------- fold dots into w_out: Mbt[b][c][h*64+j] = sum_e dots[b,h,j,e]*w_out[h*64+e][c]/SEQ
// grid 32 = (b,h), block 256 (thread = c)
__global__ __launch_bounds__(256) void make_M(const float* __restrict__ dots,
                                              const float* __restrict__ wout,
                                              u16* __restrict__ Mbt) {
  __shared__ float dl[64 * 64];
  const int bh = blockIdx.x, b = bh >> 3, h = bh & 7;
  const int c = threadIdx.x;
  for (int i = threadIdx.x; i < 4096; i += 256) dl[i] = dots[(size_t)bh * 4096 + i];
  __syncthreads();
  float accv[64];
#pragma unroll
  for (int j = 0; j < 64; ++j) accv[j] = 0.f;
  for (int e = 0; e < 64; ++e) {
    float w = wout[(h * 64 + e) * DIM + c];
#pragma unroll
    for (int j = 0; j < 64; ++j) accv[j] += dl[j * 64 + e] * w;
  }
  const float inv_n = 1.0f / (float)SEQ;
  u16* outp = Mbt + ((size_t)(b * 256 + c)) * 512 + h * 64;
#pragma unroll
  for (int j = 0; j < 64; ++j) outp[j] = f2bf(accv[j] * inv_n);
}

// ---------------- launch ----------------
extern "C" void kernel_launch(void* const* d_in, const int* in_sizes, int n_in,
                              void* d_out, int out_size, void* d_ws, size_t ws_size,
                              hipStream_t stream) {
  const float* x     = (const float*)d_in[0];
  const float* w_qkv = (const float*)d_in[1];
  const float* w_out = (const float*)d_in[2];
  const float* b_out = (const float*)d_in[3];
  float* out = (float*)d_out;

  char* ws = (char*)d_ws;
  size_t off = 0;
  u16* xb   = (u16*)(ws + off); off += (size_t)ROWS * DIM * 2;        // 16.78 MB
  u16* wqT  = (u16*)(ws + off); off += (size_t)QKVC * DIM * 2;        // 0.79 MB
  u16* qkvb = (u16*)(ws + off); off += (size_t)ROWS * QKVC * 2;       // 100.7 MB
  float* dots = (float*)(ws + off); off += (size_t)32 * 64 * 64 * 4;  // 0.5 MB
  u16* Mbt  = (u16*)(ws + off); off += (size_t)BATCH * 256 * 512 * 2; // 1 MB

  hipMemsetAsync(dots, 0, (size_t)32 * 64 * 64 * 4, stream);
  cvt_x<<<(ROWS * DIM) / 4 / 256, 256, 0, stream>>>(x, xb, ROWS * DIM);
  cvt_wqkvT<<<(QKVC * DIM) / 256, 256, 0, stream>>>(w_qkv, wqT);
  gemm1<<<dim3(ROWS / 128, QKVC / 128), 256, 0, stream>>>(xb, wqT, qkvb);
  norm_dots<<<dim3(32, 8), 256, 0, stream>>>(qkvb, dots);
  make_M<<<32, 256, 0, stream>>>(dots, w_out, Mbt);
  gemm2<<<dim3(ROWS / 128, DIM / 128), 256, 0, stream>>>(qkvb, Mbt, b_out, out);
}

// Round 2
// 272.243 us; speedup vs baseline: 1.4532x; 1.4532x over previous
//
#include <hip/hip_runtime.h>
#include <hip/hip_bf16.h>
#include <stdint.h>

#define HEADS 8
#define DHEAD 64
#define BATCH 4
#define SEQ   8192
#define DIM   256
#define INNER 512
#define QKVC  1536
#define ROWS  32768   // BATCH*SEQ
#define EPS   1e-5f

typedef unsigned short u16;
typedef __attribute__((ext_vector_type(8))) short bf16x8;
typedef __attribute__((ext_vector_type(4))) float f32x4;

#define AS1 __attribute__((address_space(1)))
#define AS3 __attribute__((address_space(3)))

__device__ __forceinline__ void async16(const void* g, void* l) {
  __builtin_amdgcn_global_load_lds((AS1 unsigned int*)g, (AS3 unsigned int*)l, 16, 0, 0);
}

__device__ __forceinline__ float bf2f(u16 u) {
  union { uint32_t i; float f; } v; v.i = ((uint32_t)u) << 16; return v.f;
}
__device__ __forceinline__ u16 f2bf(float f) {
  union { float f; uint32_t i; } v; v.f = f;
  uint32_t x = v.i;
  return (u16)((x + 0x7fffu + ((x >> 16) & 1u)) >> 16);  // RNE
}

// ---------------- conversion kernels ----------------
__global__ void cvt_x(const float* __restrict__ x, u16* __restrict__ xb, int n) {
  int i = (blockIdx.x * blockDim.x + threadIdx.x) * 4;
  if (i < n) {
    float4 v = *(const float4*)(x + i);
    u16 o0 = f2bf(v.x), o1 = f2bf(v.y), o2 = f2bf(v.z), o3 = f2bf(v.w);
    ushort4 o; o.x = o0; o.y = o1; o.z = o2; o.w = o3;
    *(ushort4*)(xb + i) = o;
  }
}

// w_qkv [256,1536] fp32 -> wT [1536,256] bf16
__global__ void cvt_wqkvT(const float* __restrict__ w, u16* __restrict__ wt) {
  int id = blockIdx.x * blockDim.x + threadIdx.x;  // 0..393215
  int n = id >> 8;     // 0..1535
  int k = id & 255;    // 0..255
  wt[id] = f2bf(w[k * QKVC + n]);
}

// ---------------- shared GEMM tile core (C = A @ Bt^T), 128x128 tile, BK=64 ----------------
__device__ __forceinline__ void gemm_tile(const u16* __restrict__ A, int lda,
                                          const u16* __restrict__ Bt, int ldb,
                                          int K, int row0, int col0,
                                          u16* sA, u16* sB, f32x4 acc[4][4]) {
  const int tid = threadIdx.x, lane = tid & 63, wave = tid >> 6;
  const int mr = (wave >> 1) * 64, nc = (wave & 1) * 64;
  for (int kk = 0; kk < K; kk += 64) {
#pragma unroll
    for (int it = 0; it < 4; ++it) {
      int s = it * 256 + tid;
      int r = s >> 3, c = (s & 7) << 3;
      // LDS dest: wave-uniform base; HW adds lane*16
      async16(A + (size_t)(row0 + r) * lda + kk + c, sA + (it * 256 + wave * 64) * 8);
      async16(Bt + (size_t)(col0 + r) * ldb + kk + c, sB + (it * 256 + wave * 64) * 8);
    }
    __syncthreads();
#pragma unroll
    for (int ks = 0; ks < 2; ++ks) {
      bf16x8 af[4], bfr[4];
#pragma unroll
      for (int f = 0; f < 4; ++f) {
        af[f]  = *(const bf16x8*)&sA[(mr + f * 16 + (lane & 15)) * 64 + ks * 32 + (lane >> 4) * 8];
        bfr[f] = *(const bf16x8*)&sB[(nc + f * 16 + (lane & 15)) * 64 + ks * 32 + (lane >> 4) * 8];
      }
#pragma unroll
      for (int fm = 0; fm < 4; ++fm)
#pragma unroll
        for (int fn = 0; fn < 4; ++fn)
          acc[fm][fn] = __builtin_amdgcn_mfma_f32_16x16x32_bf16(af[fm], bfr[fn], acc[fm][fn], 0, 0, 0);
    }
    __syncthreads();
  }
}

// GEMM1: qkv = x @ w_qkv ; A=[32768,256] bf16, Bt=[1536,256] bf16, C bf16 [32768,1536]
__global__ __launch_bounds__(256) void gemm1(const u16* __restrict__ A,
                                             const u16* __restrict__ Bt,
                                             u16* __restrict__ C) {
  __shared__ alignas(16) u16 sA[128 * 64];
  __shared__ alignas(16) u16 sB[128 * 64];
  const int lane = threadIdx.x & 63, wave = threadIdx.x >> 6;
  const int row0 = blockIdx.x * 128, col0 = blockIdx.y * 128;
  f32x4 acc[4][4];
#pragma unroll
  for (int i = 0; i < 4; ++i)
#pragma unroll
    for (int j = 0; j < 4; ++j) acc[i][j] = (f32x4){0.f, 0.f, 0.f, 0.f};

  gemm_tile(A, DIM, Bt, DIM, DIM, row0, col0, sA, sB, acc);

  const int mr = (wave >> 1) * 64, nc = (wave & 1) * 64;
#pragma unroll
  for (int fm = 0; fm < 4; ++fm) {
    int rbase = row0 + mr + fm * 16 + (lane >> 4) * 4;
#pragma unroll
    for (int fn = 0; fn < 4; ++fn) {
      int col = col0 + nc + fn * 16 + (lane & 15);
#pragma unroll
      for (int r = 0; r < 4; ++r)
        C[(size_t)(rbase + r) * QKVC + col] = f2bf(acc[fm][fn][r]);
    }
  }
}

// GEMM2: out[b] = q[b] @ Mbt[b]^T + bias ; A = qkv (first 512 cols), Bt = Mbt[b] [256,512]
__global__ __launch_bounds__(256) void gemm2(const u16* __restrict__ A,
                                             const u16* __restrict__ Mbt,
                                             const float* __restrict__ bias,
                                             float* __restrict__ out) {
  __shared__ alignas(16) u16 sA[128 * 64];
  __shared__ alignas(16) u16 sB[128 * 64];
  const int lane = threadIdx.x & 63, wave = threadIdx.x >> 6;
  const int row0 = blockIdx.x * 128, col0 = blockIdx.y * 128;
  const int b = blockIdx.x >> 6;  // 8192/128 = 64 row-blocks per batch
  const u16* BtB = Mbt + (size_t)b * 256 * 512;
  f32x4 acc[4][4];
#pragma unroll
  for (int i = 0; i < 4; ++i)
#pragma unroll
    for (int j = 0; j < 4; ++j) acc[i][j] = (f32x4){0.f, 0.f, 0.f, 0.f};

  gemm_tile(A, QKVC, BtB, INNER, INNER, row0, col0, sA, sB, acc);

  const int mr = (wave >> 1) * 64, nc = (wave & 1) * 64;
#pragma unroll
  for (int fm = 0; fm < 4; ++fm) {
    int rbase = row0 + mr + fm * 16 + (lane >> 4) * 4;
#pragma unroll
    for (int fn = 0; fn < 4; ++fn) {
      int col = col0 + nc + fn * 16 + (lane & 15);
      float bb = bias[col];
#pragma unroll
      for (int r = 0; r < 4; ++r)
        out[(size_t)(rbase + r) * DIM + col] = acc[fm][fn][r] + bb;
    }
  }
}

// ---------------- instance-norm + dots reduction ----------------
// Thread-per-token: each thread normalizes one token's k OR v (64 values,
// serial in registers — no cross-lane ops). grid (32 = b*h, 64 chunks of 128
// tokens), block 256: threads 0..127 = k for tok 0..127, threads 128..255 = v.
__global__ __launch_bounds__(256) void norm_dots(const u16* __restrict__ qkv,
                                                 float* __restrict__ dots) {
  __shared__ alignas(16) u16 knT[64 * 136];
  __shared__ alignas(16) u16 vnT[64 * 136];
  const int bh = blockIdx.x, b = bh >> 3, h = bh & 7;
  const int tid = threadIdx.x, lane = tid & 63, wave = tid >> 6;
  const int tok = tid & 127;         // token within chunk
  const int half = tid >> 7;         // 0 = k, 1 = v
  const int nbase = blockIdx.y * 128;

  // phase 1: load 64 contiguous bf16 (8x16B), stats in registers
  const int row = b * SEQ + nbase + tok;
  const bf16x8* p = (const bf16x8*)(qkv + (size_t)row * QKVC + 512 + half * 512 + h * 64);
  bf16x8 raw[8];
#pragma unroll
  for (int i = 0; i < 8; ++i) raw[i] = p[i];
  float s = 0.f, s2 = 0.f;
#pragma unroll
  for (int i = 0; i < 8; ++i)
#pragma unroll
    for (int j = 0; j < 8; ++j) {
      float f = bf2f((u16)raw[i][j]);
      s += f;
      s2 = fmaf(f, f, s2);
    }
  float mu = s * (1.f / 64.f);
  float var = s2 * (1.f / 64.f) - mu * mu;
  float rs = rsqrtf(var + EPS);
  u16* dst = half ? vnT : knT;
  // transposed write: lanes index tok -> contiguous 128B per wave-write, conflict-free
#pragma unroll
  for (int i = 0; i < 8; ++i)
#pragma unroll
    for (int j = 0; j < 8; ++j) {
      int d = i * 8 + j;
      dst[d * 136 + tok] = f2bf((bf2f((u16)raw[i][j]) - mu) * rs);
    }
  __syncthreads();

  // phase 2: dots[d][e] += sum_tok knT[d][tok]*vnT[e][tok] via MFMA (K=128 tokens)
  f32x4 acc[4];
#pragma unroll
  for (int f = 0; f < 4; ++f) acc[f] = (f32x4){0.f, 0.f, 0.f, 0.f};
#pragma unroll
  for (int ks = 0; ks < 4; ++ks) {
    bf16x8 a = *(const bf16x8*)&knT[(wave * 16 + (lane & 15)) * 136 + ks * 32 + (lane >> 4) * 8];
#pragma unroll
    for (int fn = 0; fn < 4; ++fn) {
      bf16x8 bb = *(const bf16x8*)&vnT[(fn * 16 + (lane & 15)) * 136 + ks * 32 + (lane >> 4) * 8];
      acc[fn] = __builtin_amdgcn_mfma_f32_16x16x32_bf16(a, bb, acc[fn], 0, 0, 0);
    }
  }

  float* dbase = dots + (size_t)bh * 4096;
#pragma unroll
  for (int fn = 0; fn < 4; ++fn) {
    int e = fn * 16 + (lane & 15);
#pragma unroll
    for (int r = 0; r < 4; ++r) {
      int d = wave * 16 + (lane >> 4) * 4 + r;
      atomicAdd(dbase + d * 64 + e, acc[fn][r]);
    }
  }
}

// ---------------- fold dots into w_out: Mbt[b][c][h*64+j] = sum_e dots[b,h,j,e]*w_out[h*64+e][c]/SEQ
// grid 32 = (b,h), block 256 (thread = c)
__global__ __launch_bounds__(256) void make_M(const float* __restrict__ dots,
                                              const float* __restrict__ wout,
                                              u16* __restrict__ Mbt) {
  __shared__ float dl[64 * 64];
  const int bh = blockIdx.x, b = bh >> 3, h = bh & 7;
  const int c = threadIdx.x;
  for (int i = threadIdx.x; i < 4096; i += 256) dl[i] = dots[(size_t)bh * 4096 + i];
  __syncthreads();
  float accv[64];
#pragma unroll
  for (int j = 0; j < 64; ++j) accv[j] = 0.f;
  for (int e = 0; e < 64; ++e) {
    float w = wout[(h * 64 + e) * DIM + c];
#pragma unroll
    for (int j = 0; j < 64; ++j) accv[j] += dl[j * 64 + e] * w;
  }
  const float inv_n = 1.0f / (float)SEQ;
  u16* outp = Mbt + ((size_t)(b * 256 + c)) * 512 + h * 64;
#pragma unroll
  for (int j = 0; j < 64; ++j) outp[j] = f2bf(accv[j] * inv_n);
}

// ---------------- launch ----------------
extern "C" void kernel_launch(void* const* d_in, const int* in_sizes, int n_in,
                              void* d_out, int out_size, void* d_ws, size_t ws_size,
                              hipStream_t stream) {
  const float* x     = (const float*)d_in[0];
  const float* w_qkv = (const float*)d_in[1];
  const float* w_out = (const float*)d_in[2];
  const float* b_out = (const float*)d_in[3];
  float* out = (float*)d_out;

  char* ws = (char*)d_ws;
  size_t off = 0;
  u16* xb   = (u16*)(ws + off); off += (size_t)ROWS * DIM * 2;        // 16.78 MB
  u16* wqT  = (u16*)(ws + off); off += (size_t)QKVC * DIM * 2;        // 0.79 MB
  u16* qkvb = (u16*)(ws + off); off += (size_t)ROWS * QKVC * 2;       // 100.7 MB
  float* dots = (float*)(ws + off); off += (size_t)32 * 64 * 64 * 4;  // 0.5 MB
  u16* Mbt  = (u16*)(ws + off); off += (size_t)BATCH * 256 * 512 * 2; // 1 MB

  hipMemsetAsync(dots, 0, (size_t)32 * 64 * 64 * 4, stream);
  cvt_x<<<(ROWS * DIM) / 4 / 256, 256, 0, stream>>>(x, xb, ROWS * DIM);
  cvt_wqkvT<<<(QKVC * DIM) / 256, 256, 0, stream>>>(w_qkv, wqT);
  gemm1<<<dim3(ROWS / 128, QKVC / 128), 256, 0, stream>>>(xb, wqT, qkvb);
  norm_dots<<<dim3(32, 64), 256, 0, stream>>>(qkvb, dots);
  make_M<<<32, 256, 0, stream>>>(dots, w_out, Mbt);
  gemm2<<<dim3(ROWS / 128, DIM / 128), 256, 0, stream>>>(qkvb, Mbt, b_out, out);
}

// Round 3
// 215.802 us; speedup vs baseline: 1.8333x; 1.2615x over previous
//
#include <hip/hip_runtime.h>
#include <hip/hip_bf16.h>
#include <stdint.h>

#define HEADS 8
#define DHEAD 64
#define BATCH 4
#define SEQ   8192
#define DIM   256
#define INNER 512
#define QKVC  1536
#define ROWS  32768   // BATCH*SEQ
#define EPS   1e-5f

typedef unsigned short u16;
typedef __attribute__((ext_vector_type(8))) short bf16x8;
typedef __attribute__((ext_vector_type(4))) float f32x4;

#define AS1 __attribute__((address_space(1)))
#define AS3 __attribute__((address_space(3)))

__device__ __forceinline__ void async16(const void* g, void* l) {
  __builtin_amdgcn_global_load_lds((AS1 unsigned int*)g, (AS3 unsigned int*)l, 16, 0, 0);
}

__device__ __forceinline__ float bf2f(u16 u) {
  union { uint32_t i; float f; } v; v.i = ((uint32_t)u) << 16; return v.f;
}
__device__ __forceinline__ u16 f2bf(float f) {
  union { float f; uint32_t i; } v; v.f = f;
  uint32_t x = v.i;
  return (u16)((x + 0x7fffu + ((x >> 16) & 1u)) >> 16);  // RNE
}

// ---------------- conversion kernels ----------------
__global__ void cvt_x(const float* __restrict__ x, u16* __restrict__ xb, int n) {
  int i = (blockIdx.x * blockDim.x + threadIdx.x) * 4;
  if (i < n) {
    float4 v = *(const float4*)(x + i);
    u16 o0 = f2bf(v.x), o1 = f2bf(v.y), o2 = f2bf(v.z), o3 = f2bf(v.w);
    ushort4 o; o.x = o0; o.y = o1; o.z = o2; o.w = o3;
    *(ushort4*)(xb + i) = o;
  }
}

// w_qkv [256,1536] fp32 -> wT [1536,256] bf16
__global__ void cvt_wqkvT(const float* __restrict__ w, u16* __restrict__ wt) {
  int id = blockIdx.x * blockDim.x + threadIdx.x;  // 0..393215
  int n = id >> 8;     // 0..1535
  int k = id & 255;    // 0..255
  wt[id] = f2bf(w[k * QKVC + n]);
}

// ---------------- shared GEMM tile core (C = A @ Bt^T), 128x128 tile, BK=64 ----------------
__device__ __forceinline__ void gemm_tile(const u16* __restrict__ A, int lda,
                                          const u16* __restrict__ Bt, int ldb,
                                          int K, int row0, int col0,
                                          u16* sA, u16* sB, f32x4 acc[4][4]) {
  const int tid = threadIdx.x, lane = tid & 63, wave = tid >> 6;
  const int mr = (wave >> 1) * 64, nc = (wave & 1) * 64;
  for (int kk = 0; kk < K; kk += 64) {
#pragma unroll
    for (int it = 0; it < 4; ++it) {
      int s = it * 256 + tid;
      int r = s >> 3, c = (s & 7) << 3;
      // LDS dest: wave-uniform base; HW adds lane*16
      async16(A + (size_t)(row0 + r) * lda + kk + c, sA + (it * 256 + wave * 64) * 8);
      async16(Bt + (size_t)(col0 + r) * ldb + kk + c, sB + (it * 256 + wave * 64) * 8);
    }
    __syncthreads();
#pragma unroll
    for (int ks = 0; ks < 2; ++ks) {
      bf16x8 af[4], bfr[4];
#pragma unroll
      for (int f = 0; f < 4; ++f) {
        af[f]  = *(const bf16x8*)&sA[(mr + f * 16 + (lane & 15)) * 64 + ks * 32 + (lane >> 4) * 8];
        bfr[f] = *(const bf16x8*)&sB[(nc + f * 16 + (lane & 15)) * 64 + ks * 32 + (lane >> 4) * 8];
      }
#pragma unroll
      for (int fm = 0; fm < 4; ++fm)
#pragma unroll
        for (int fn = 0; fn < 4; ++fn)
          acc[fm][fn] = __builtin_amdgcn_mfma_f32_16x16x32_bf16(af[fm], bfr[fn], acc[fm][fn], 0, 0, 0);
    }
    __syncthreads();
  }
}

// GEMM1: qkv = x @ w_qkv ; A=[32768,256] bf16, Bt=[1536,256] bf16, C bf16 [32768,1536]
__global__ __launch_bounds__(256) void gemm1(const u16* __restrict__ A,
                                             const u16* __restrict__ Bt,
                                             u16* __restrict__ C) {
  __shared__ alignas(16) u16 sA[128 * 64];
  __shared__ alignas(16) u16 sB[128 * 64];
  const int lane = threadIdx.x & 63, wave = threadIdx.x >> 6;
  const int row0 = blockIdx.x * 128, col0 = blockIdx.y * 128;
  f32x4 acc[4][4];
#pragma unroll
  for (int i = 0; i < 4; ++i)
#pragma unroll
    for (int j = 0; j < 4; ++j) acc[i][j] = (f32x4){0.f, 0.f, 0.f, 0.f};

  gemm_tile(A, DIM, Bt, DIM, DIM, row0, col0, sA, sB, acc);

  const int mr = (wave >> 1) * 64, nc = (wave & 1) * 64;
#pragma unroll
  for (int fm = 0; fm < 4; ++fm) {
    int rbase = row0 + mr + fm * 16 + (lane >> 4) * 4;
#pragma unroll
    for (int fn = 0; fn < 4; ++fn) {
      int col = col0 + nc + fn * 16 + (lane & 15);
#pragma unroll
      for (int r = 0; r < 4; ++r)
        C[(size_t)(rbase + r) * QKVC + col] = f2bf(acc[fm][fn][r]);
    }
  }
}

// GEMM2: out[b] = q[b] @ Mbt[b]^T + bias ; A = qkv (first 512 cols), Bt = Mbt[b] [256,512]
__global__ __launch_bounds__(256) void gemm2(const u16* __restrict__ A,
                                             const u16* __restrict__ Mbt,
                                             const float* __restrict__ bias,
                                             float* __restrict__ out) {
  __shared__ alignas(16) u16 sA[128 * 64];
  __shared__ alignas(16) u16 sB[128 * 64];
  const int lane = threadIdx.x & 63, wave = threadIdx.x >> 6;
  const int row0 = blockIdx.x * 128, col0 = blockIdx.y * 128;
  const int b = blockIdx.x >> 6;  // 8192/128 = 64 row-blocks per batch
  const u16* BtB = Mbt + (size_t)b * 256 * 512;
  f32x4 acc[4][4];
#pragma unroll
  for (int i = 0; i < 4; ++i)
#pragma unroll
    for (int j = 0; j < 4; ++j) acc[i][j] = (f32x4){0.f, 0.f, 0.f, 0.f};

  gemm_tile(A, QKVC, BtB, INNER, INNER, row0, col0, sA, sB, acc);

  const int mr = (wave >> 1) * 64, nc = (wave & 1) * 64;
#pragma unroll
  for (int fm = 0; fm < 4; ++fm) {
    int rbase = row0 + mr + fm * 16 + (lane >> 4) * 4;
#pragma unroll
    for (int fn = 0; fn < 4; ++fn) {
      int col = col0 + nc + fn * 16 + (lane & 15);
      float bb = bias[col];
#pragma unroll
      for (int r = 0; r < 4; ++r)
        out[(size_t)(rbase + r) * DIM + col] = acc[fm][fn][r] + bb;
    }
  }
}

// ---------------- instance-norm + dots reduction ----------------
// Thread-per-token: each thread normalizes one token's k OR v (64 values,
// serial in registers — no cross-lane ops). grid (32 = b*h, 64 chunks of 128
// tokens), block 256: threads 0..127 = k for tok 0..127, threads 128..255 = v.
__global__ __launch_bounds__(256) void norm_dots(const u16* __restrict__ qkv,
                                                 float* __restrict__ dots) {
  __shared__ alignas(16) u16 knT[64 * 136];
  __shared__ alignas(16) u16 vnT[64 * 136];
  const int bh = blockIdx.x, b = bh >> 3, h = bh & 7;
  const int tid = threadIdx.x, lane = tid & 63, wave = tid >> 6;
  const int tok = tid & 127;         // token within chunk
  const int half = tid >> 7;         // 0 = k, 1 = v
  const int nbase = blockIdx.y * 128;

  // phase 1: load 64 contiguous bf16 (8x16B), stats in registers
  const int row = b * SEQ + nbase + tok;
  const bf16x8* p = (const bf16x8*)(qkv + (size_t)row * QKVC + 512 + half * 512 + h * 64);
  bf16x8 raw[8];
#pragma unroll
  for (int i = 0; i < 8; ++i) raw[i] = p[i];
  float s = 0.f, s2 = 0.f;
#pragma unroll
  for (int i = 0; i < 8; ++i)
#pragma unroll
    for (int j = 0; j < 8; ++j) {
      float f = bf2f((u16)raw[i][j]);
      s += f;
      s2 = fmaf(f, f, s2);
    }
  float mu = s * (1.f / 64.f);
  float var = s2 * (1.f / 64.f) - mu * mu;
  float rs = rsqrtf(var + EPS);
  u16* dst = half ? vnT : knT;
  // transposed write: lanes index tok -> contiguous 128B per wave-write, conflict-free
#pragma unroll
  for (int i = 0; i < 8; ++i)
#pragma unroll
    for (int j = 0; j < 8; ++j) {
      int d = i * 8 + j;
      dst[d * 136 + tok] = f2bf((bf2f((u16)raw[i][j]) - mu) * rs);
    }
  __syncthreads();

  // phase 2: dots[d][e] += sum_tok knT[d][tok]*vnT[e][tok] via MFMA (K=128 tokens)
  f32x4 acc[4];
#pragma unroll
  for (int f = 0; f < 4; ++f) acc[f] = (f32x4){0.f, 0.f, 0.f, 0.f};
#pragma unroll
  for (int ks = 0; ks < 4; ++ks) {
    bf16x8 a = *(const bf16x8*)&knT[(wave * 16 + (lane & 15)) * 136 + ks * 32 + (lane >> 4) * 8];
#pragma unroll
    for (int fn = 0; fn < 4; ++fn) {
      bf16x8 bb = *(const bf16x8*)&vnT[(fn * 16 + (lane & 15)) * 136 + ks * 32 + (lane >> 4) * 8];
      acc[fn] = __builtin_amdgcn_mfma_f32_16x16x32_bf16(a, bb, acc[fn], 0, 0, 0);
    }
  }

  float* dbase = dots + (size_t)bh * 4096;
#pragma unroll
  for (int fn = 0; fn < 4; ++fn) {
    int e = fn * 16 + (lane & 15);
#pragma unroll
    for (int r = 0; r < 4; ++r) {
      int d = wave * 16 + (lane >> 4) * 4 + r;
      atomicAdd(dbase + d * 64 + e, acc[fn][r]);
    }
  }
}

// ---------------- fold dots into w_out ----------------
// Mbt[b][c][h*64+j] = sum_e dots[b,h,j,e]*w_out[h*64+e][c]/SEQ
// grid (32 = b*h, 8 j-groups), block 256 (thread = c). accv[8] stays in VGPRs
// (the R2 version's accv[64] spilled to scratch at VGPR_Count=36 -> 85 us).
__global__ __launch_bounds__(256) void make_M(const float* __restrict__ dots,
                                              const float* __restrict__ wout,
                                              u16* __restrict__ Mbt) {
  __shared__ float dl[8][64];
  const int bh = blockIdx.x, b = bh >> 3, h = bh & 7;
  const int jg = blockIdx.y;
  const int c = threadIdx.x;
  // stage dots[bh][jg*8 .. jg*8+8)[0..64) -> 512 floats
  for (int i = threadIdx.x; i < 512; i += 256)
    ((float*)dl)[i] = dots[(size_t)bh * 4096 + jg * 512 + i];
  __syncthreads();
  float accv[8];
#pragma unroll
  for (int jj = 0; jj < 8; ++jj) accv[jj] = 0.f;
  for (int e = 0; e < 64; ++e) {
    float w = wout[(h * 64 + e) * DIM + c];  // coalesced across c; dl broadcast
#pragma unroll
    for (int jj = 0; jj < 8; ++jj) accv[jj] = fmaf(dl[jj][e], w, accv[jj]);
  }
  const float inv_n = 1.0f / (float)SEQ;
  u16* outp = Mbt + ((size_t)(b * 256 + c)) * 512 + h * 64 + jg * 8;
#pragma unroll
  for (int jj = 0; jj < 8; ++jj) outp[jj] = f2bf(accv[jj] * inv_n);
}

// ---------------- launch ----------------
extern "C" void kernel_launch(void* const* d_in, const int* in_sizes, int n_in,
                              void* d_out, int out_size, void* d_ws, size_t ws_size,
                              hipStream_t stream) {
  const float* x     = (const float*)d_in[0];
  const float* w_qkv = (const float*)d_in[1];
  const float* w_out = (const float*)d_in[2];
  const float* b_out = (const float*)d_in[3];
  float* out = (float*)d_out;

  char* ws = (char*)d_ws;
  size_t off = 0;
  u16* xb   = (u16*)(ws + off); off += (size_t)ROWS * DIM * 2;        // 16.78 MB
  u16* wqT  = (u16*)(ws + off); off += (size_t)QKVC * DIM * 2;        // 0.79 MB
  u16* qkvb = (u16*)(ws + off); off += (size_t)ROWS * QKVC * 2;       // 100.7 MB
  float* dots = (float*)(ws + off); off += (size_t)32 * 64 * 64 * 4;  // 0.5 MB
  u16* Mbt  = (u16*)(ws + off); off += (size_t)BATCH * 256 * 512 * 2; // 1 MB

  hipMemsetAsync(dots, 0, (size_t)32 * 64 * 64 * 4, stream);
  cvt_x<<<(ROWS * DIM) / 4 / 256, 256, 0, stream>>>(x, xb, ROWS * DIM);
  cvt_wqkvT<<<(QKVC * DIM) / 256, 256, 0, stream>>>(w_qkv, wqT);
  gemm1<<<dim3(ROWS / 128, QKVC / 128), 256, 0, stream>>>(xb, wqT, qkvb);
  norm_dots<<<dim3(32, 64), 256, 0, stream>>>(qkvb, dots);
  make_M<<<dim3(32, 8), 256, 0, stream>>>(dots, w_out, Mbt);
  gemm2<<<dim3(ROWS / 128, DIM / 128), 256, 0, stream>>>(qkvb, Mbt, b_out, out);
}

// Round 4
// 197.046 us; speedup vs baseline: 2.0078x; 1.0952x over previous
//
#include <hip/hip_runtime.h>
#include <hip/hip_bf16.h>
#include <stdint.h>

#define HEADS 8
#define DHEAD 64
#define BATCH 4
#define SEQ   8192
#define DIM   256
#define INNER 512
#define QKVC  1536
#define ROWS  32768   // BATCH*SEQ
#define EPS   1e-5f

typedef unsigned short u16;
typedef __attribute__((ext_vector_type(8))) short bf16x8;
typedef __attribute__((ext_vector_type(4))) float f32x4;

#define AS1 __attribute__((address_space(1)))
#define AS3 __attribute__((address_space(3)))

__device__ __forceinline__ void async16(const void* g, void* l) {
  __builtin_amdgcn_global_load_lds((AS1 unsigned int*)g, (AS3 unsigned int*)l, 16, 0, 0);
}

__device__ __forceinline__ float bf2f(u16 u) {
  union { uint32_t i; float f; } v; v.i = ((uint32_t)u) << 16; return v.f;
}
__device__ __forceinline__ u16 f2bf(float f) {
  union { float f; uint32_t i; } v; v.f = f;
  uint32_t x = v.i;
  return (u16)((x + 0x7fffu + ((x >> 16) & 1u)) >> 16);  // RNE
}

// ---------------- prep: cvt_x + q-weight transpose + permuted kv-weights + zero dots ----
// blocks [0,8192): xb ; [8192,8704): wqT ; [8704,9728): wkvT ; [9728,9856): zero dots
__global__ __launch_bounds__(256) void prep(const float* __restrict__ x,
                                            const float* __restrict__ w,
                                            u16* __restrict__ xb,
                                            u16* __restrict__ wqT,
                                            u16* __restrict__ wkvT,
                                            float* __restrict__ dots) {
  int bid = blockIdx.x;
  if (bid < 8192) {
    int i = (bid * 256 + threadIdx.x) * 4;
    float4 v = *(const float4*)(x + i);
    ushort4 o; o.x = f2bf(v.x); o.y = f2bf(v.y); o.z = f2bf(v.z); o.w = f2bf(v.w);
    *(ushort4*)(xb + i) = o;
  } else if (bid < 8704) {
    int id = (bid - 8192) * 256 + threadIdx.x;  // 0..131071
    int n = id >> 8, k = id & 255;
    wqT[id] = f2bf(w[k * QKVC + n]);            // q cols 0..511, transposed
  } else if (bid < 9728) {
    int id = (bid - 8704) * 256 + threadIdx.x;  // 0..262143
    int k = id & 255;
    int r = (id >> 8) & 127;                    // 0..127: 0..63=k-dim, 64..127=v-dim
    int h = id >> 15;                           // 0..7
    int oc = (r < 64) ? (512 + h * 64 + r) : (1024 + h * 64 + (r - 64));
    wkvT[id] = f2bf(w[k * QKVC + oc]);
  } else {
    int i = ((bid - 9728) * 256 + threadIdx.x) * 4;
    float4 z; z.x = 0.f; z.y = 0.f; z.z = 0.f; z.w = 0.f;
    *(float4*)(dots + i) = z;
  }
}

// ---------------- shared GEMM tile core (C = A @ Bt^T), 128x128 tile, BK=64, 256 thr ----
__device__ __forceinline__ void gemm_tile(const u16* __restrict__ A, int lda,
                                          const u16* __restrict__ Bt, int ldb,
                                          int K, int row0, int col0,
                                          u16* sA, u16* sB, f32x4 acc[4][4]) {
  const int tid = threadIdx.x, lane = tid & 63, wave = tid >> 6;
  const int mr = (wave >> 1) * 64, nc = (wave & 1) * 64;
  for (int kk = 0; kk < K; kk += 64) {
#pragma unroll
    for (int it = 0; it < 4; ++it) {
      int s = it * 256 + tid;
      int r = s >> 3, c = (s & 7) << 3;
      async16(A + (size_t)(row0 + r) * lda + kk + c, sA + (it * 256 + wave * 64) * 8);
      async16(Bt + (size_t)(col0 + r) * ldb + kk + c, sB + (it * 256 + wave * 64) * 8);
    }
    __syncthreads();
#pragma unroll
    for (int ks = 0; ks < 2; ++ks) {
      bf16x8 af[4], bfr[4];
#pragma unroll
      for (int f = 0; f < 4; ++f) {
        af[f]  = *(const bf16x8*)&sA[(mr + f * 16 + (lane & 15)) * 64 + ks * 32 + (lane >> 4) * 8];
        bfr[f] = *(const bf16x8*)&sB[(nc + f * 16 + (lane & 15)) * 64 + ks * 32 + (lane >> 4) * 8];
      }
#pragma unroll
      for (int fm = 0; fm < 4; ++fm)
#pragma unroll
        for (int fn = 0; fn < 4; ++fn)
          acc[fm][fn] = __builtin_amdgcn_mfma_f32_16x16x32_bf16(af[fm], bfr[fn], acc[fm][fn], 0, 0, 0);
    }
    __syncthreads();
  }
}

// ---------------- GEMM-Q: qb = x @ w_q ; [32768,256]@[256,512] -> bf16 [32768,512] ----
__global__ __launch_bounds__(256) void gemm_q(const u16* __restrict__ A,
                                              const u16* __restrict__ Bt,
                                              u16* __restrict__ C) {
  __shared__ alignas(16) u16 sA[128 * 64];
  __shared__ alignas(16) u16 sB[128 * 64];
  const int lane = threadIdx.x & 63, wave = threadIdx.x >> 6;
  const int row0 = blockIdx.x * 128, col0 = blockIdx.y * 128;
  f32x4 acc[4][4];
#pragma unroll
  for (int i = 0; i < 4; ++i)
#pragma unroll
    for (int j = 0; j < 4; ++j) acc[i][j] = (f32x4){0.f, 0.f, 0.f, 0.f};

  gemm_tile(A, DIM, Bt, DIM, DIM, row0, col0, sA, sB, acc);

  const int mr = (wave >> 1) * 64, nc = (wave & 1) * 64;
#pragma unroll
  for (int fm = 0; fm < 4; ++fm) {
    int rbase = row0 + mr + fm * 16 + (lane >> 4) * 4;
#pragma unroll
    for (int fn = 0; fn < 4; ++fn) {
      int col = col0 + nc + fn * 16 + (lane & 15);
#pragma unroll
      for (int r = 0; r < 4; ++r)
        C[(size_t)(rbase + r) * INNER + col] = f2bf(acc[fm][fn][r]);
    }
  }
}

// ---------------- GEMM-KV + instance norm + dots, fully fused ----------------
// grid (256 row-tiles, 8 heads). Per block: 128 tokens x (64 k | 64 v) tile of
// head h computed by MFMA; tile -> LDS bf16; thread-per-(token,half) norm;
// transposed knT/vnT; dots MFMA; atomicAdd into dots[b*8+h]. k/v never hit HBM.
__global__ __launch_bounds__(256) void gemm_kv_dots(const u16* __restrict__ A,
                                                    const u16* __restrict__ wkvT,
                                                    float* __restrict__ dots) {
  // region1 (17408 u16): sA[128*64] + sB[128*64] during K-loop, then sC[128][136]
  // region2 (17408 u16): knT[64][136] + vnT[64][136]
  __shared__ alignas(16) u16 smem[17408 + 17408];  // 69632 B -> 2 blocks/CU
  u16* sA  = smem;
  u16* sB  = smem + 8192;
  u16* sC  = smem;                 // aliases sA/sB after K-loop
  u16* knT = smem + 17408;
  u16* vnT = smem + 17408 + 8704;

  const int tid = threadIdx.x, lane = tid & 63, wave = tid >> 6;
  const int row0 = blockIdx.x * 128;
  const int h = blockIdx.y;
  const u16* Bt = wkvT + h * 128 * 256;

  f32x4 acc[4][4];
#pragma unroll
  for (int i = 0; i < 4; ++i)
#pragma unroll
    for (int j = 0; j < 4; ++j) acc[i][j] = (f32x4){0.f, 0.f, 0.f, 0.f};

  gemm_tile(A, DIM, Bt, DIM, DIM, row0, 0, sA, sB, acc);

  // epilogue 1: acc (fp32) -> sC bf16 [128 tokens][136 stride], cols 0..63=k, 64..127=v
  const int mr = (wave >> 1) * 64, nc = (wave & 1) * 64;
#pragma unroll
  for (int fm = 0; fm < 4; ++fm) {
    int rbase = mr + fm * 16 + (lane >> 4) * 4;
#pragma unroll
    for (int fn = 0; fn < 4; ++fn) {
      int col = nc + fn * 16 + (lane & 15);
#pragma unroll
      for (int r = 0; r < 4; ++r)
        sC[(rbase + r) * 136 + col] = f2bf(acc[fm][fn][r]);
    }
  }
  __syncthreads();

  // epilogue 2: thread-per-(token,half) instance norm, write transposed
  const int tok = tid & 127, half = tid >> 7;
  const bf16x8* src = (const bf16x8*)(sC + tok * 136 + half * 64);
  bf16x8 raw[8];
#pragma unroll
  for (int i = 0; i < 8; ++i) raw[i] = src[i];
  float s = 0.f, s2 = 0.f;
#pragma unroll
  for (int i = 0; i < 8; ++i)
#pragma unroll
    for (int j = 0; j < 8; ++j) {
      float f = bf2f((u16)raw[i][j]);
      s += f;
      s2 = fmaf(f, f, s2);
    }
  float mu = s * (1.f / 64.f);
  float var = s2 * (1.f / 64.f) - mu * mu;
  float rs = rsqrtf(var + EPS);
  u16* dst = half ? vnT : knT;
#pragma unroll
  for (int i = 0; i < 8; ++i)
#pragma unroll
    for (int j = 0; j < 8; ++j)
      dst[(i * 8 + j) * 136 + tok] = f2bf((bf2f((u16)raw[i][j]) - mu) * rs);
  __syncthreads();

  // epilogue 3: dots[d][e] += sum_tok knT[d][tok]*vnT[e][tok] via MFMA (K=128)
  f32x4 dacc[4];
#pragma unroll
  for (int f = 0; f < 4; ++f) dacc[f] = (f32x4){0.f, 0.f, 0.f, 0.f};
#pragma unroll
  for (int ks = 0; ks < 4; ++ks) {
    bf16x8 a = *(const bf16x8*)&knT[(wave * 16 + (lane & 15)) * 136 + ks * 32 + (lane >> 4) * 8];
#pragma unroll
    for (int fn = 0; fn < 4; ++fn) {
      bf16x8 bb = *(const bf16x8*)&vnT[(fn * 16 + (lane & 15)) * 136 + ks * 32 + (lane >> 4) * 8];
      dacc[fn] = __builtin_amdgcn_mfma_f32_16x16x32_bf16(a, bb, dacc[fn], 0, 0, 0);
    }
  }

  const int b = blockIdx.x >> 6;  // 8192/128 = 64 row-tiles per batch
  float* dbase = dots + (size_t)(b * 8 + h) * 4096;
#pragma unroll
  for (int fn = 0; fn < 4; ++fn) {
    int e = fn * 16 + (lane & 15);
#pragma unroll
    for (int r = 0; r < 4; ++r) {
      int d = wave * 16 + (lane >> 4) * 4 + r;
      atomicAdd(dbase + d * 64 + e, dacc[fn][r]);
    }
  }
}

// ---------------- fold dots into w_out ----------------
// Mbt[b][c][h*64+j] = sum_e dots[b,h,j,e]*w_out[h*64+e][c]/SEQ
__global__ __launch_bounds__(256) void make_M(const float* __restrict__ dots,
                                              const float* __restrict__ wout,
                                              u16* __restrict__ Mbt) {
  __shared__ float dl[8][64];
  const int bh = blockIdx.x, b = bh >> 3, h = bh & 7;
  const int jg = blockIdx.y;
  const int c = threadIdx.x;
  for (int i = threadIdx.x; i < 512; i += 256)
    ((float*)dl)[i] = dots[(size_t)bh * 4096 + jg * 512 + i];
  __syncthreads();
  float accv[8];
#pragma unroll
  for (int jj = 0; jj < 8; ++jj) accv[jj] = 0.f;
  for (int e = 0; e < 64; ++e) {
    float w = wout[(h * 64 + e) * DIM + c];
#pragma unroll
    for (int jj = 0; jj < 8; ++jj) accv[jj] = fmaf(dl[jj][e], w, accv[jj]);
  }
  const float inv_n = 1.0f / (float)SEQ;
  u16* outp = Mbt + ((size_t)(b * 256 + c)) * 512 + h * 64 + jg * 8;
#pragma unroll
  for (int jj = 0; jj < 8; ++jj) outp[jj] = f2bf(accv[jj] * inv_n);
}

// ---------------- GEMM2: out[b] = q[b] @ Mbt[b]^T + bias ; 128x256 tile, 512 thr ----
__global__ __launch_bounds__(512) void gemm2(const u16* __restrict__ qb,
                                             const u16* __restrict__ Mbt,
                                             const float* __restrict__ bias,
                                             float* __restrict__ out) {
  __shared__ alignas(16) u16 sA[128 * 64];   // 16 KB
  __shared__ alignas(16) u16 sB[256 * 64];   // 32 KB
  const int tid = threadIdx.x, lane = tid & 63, wave = tid >> 6;  // 8 waves
  const int row0 = blockIdx.x * 128;
  const int b = blockIdx.x >> 6;
  const u16* Bt = Mbt + (size_t)b * 256 * 512;   // [256 cols][512 k]
  const int mr = (wave >> 2) * 64, nc = (wave & 3) * 64;
  f32x4 acc[4][4];
#pragma unroll
  for (int i = 0; i < 4; ++i)
#pragma unroll
    for (int j = 0; j < 4; ++j) acc[i][j] = (f32x4){0.f, 0.f, 0.f, 0.f};

  for (int kk = 0; kk < INNER; kk += 64) {
#pragma unroll
    for (int it = 0; it < 2; ++it) {
      int s = it * 512 + tid;
      int r = s >> 3, c = (s & 7) << 3;
      async16(qb + (size_t)(row0 + r) * INNER + kk + c, sA + (it * 512 + wave * 64) * 8);
    }
#pragma unroll
    for (int it = 0; it < 4; ++it) {
      int s = it * 512 + tid;
      int r = s >> 3, c = (s & 7) << 3;
      async16(Bt + (size_t)r * INNER + kk + c, sB + (it * 512 + wave * 64) * 8);
    }
    __syncthreads();
#pragma unroll
    for (int ks = 0; ks < 2; ++ks) {
      bf16x8 af[4], bfr[4];
#pragma unroll
      for (int f = 0; f < 4; ++f) {
        af[f]  = *(const bf16x8*)&sA[(mr + f * 16 + (lane & 15)) * 64 + ks * 32 + (lane >> 4) * 8];
        bfr[f] = *(const bf16x8*)&sB[(nc + f * 16 + (lane & 15)) * 64 + ks * 32 + (lane >> 4) * 8];
      }
#pragma unroll
      for (int fm = 0; fm < 4; ++fm)
#pragma unroll
        for (int fn = 0; fn < 4; ++fn)
          acc[fm][fn] = __builtin_amdgcn_mfma_f32_16x16x32_bf16(af[fm], bfr[fn], acc[fm][fn], 0, 0, 0);
    }
    __syncthreads();
  }

#pragma unroll
  for (int fm = 0; fm < 4; ++fm) {
    int rbase = row0 + mr + fm * 16 + (lane >> 4) * 4;
#pragma unroll
    for (int fn = 0; fn < 4; ++fn) {
      int col = nc + fn * 16 + (lane & 15);
      float bb = bias[col];
#pragma unroll
      for (int r = 0; r < 4; ++r)
        out[(size_t)(rbase + r) * DIM + col] = acc[fm][fn][r] + bb;
    }
  }
}

// ---------------- launch ----------------
extern "C" void kernel_launch(void* const* d_in, const int* in_sizes, int n_in,
                              void* d_out, int out_size, void* d_ws, size_t ws_size,
                              hipStream_t stream) {
  const float* x     = (const float*)d_in[0];
  const float* w_qkv = (const float*)d_in[1];
  const float* w_out = (const float*)d_in[2];
  const float* b_out = (const float*)d_in[3];
  float* out = (float*)d_out;

  char* ws = (char*)d_ws;
  size_t off = 0;
  u16* xb    = (u16*)(ws + off); off += (size_t)ROWS * DIM * 2;          // 16.78 MB
  u16* wqT   = (u16*)(ws + off); off += (size_t)INNER * DIM * 2;         // 0.26 MB
  u16* wkvT  = (u16*)(ws + off); off += (size_t)HEADS * 128 * DIM * 2;   // 0.52 MB
  u16* qb    = (u16*)(ws + off); off += (size_t)ROWS * INNER * 2;        // 33.55 MB
  float* dots = (float*)(ws + off); off += (size_t)32 * 64 * 64 * 4;     // 0.52 MB
  u16* Mbt   = (u16*)(ws + off); off += (size_t)BATCH * 256 * 512 * 2;   // 1.05 MB

  prep<<<9856, 256, 0, stream>>>(x, w_qkv, xb, wqT, wkvT, dots);
  gemm_q<<<dim3(ROWS / 128, 4), 256, 0, stream>>>(xb, wqT, qb);
  gemm_kv_dots<<<dim3(ROWS / 128, HEADS), 256, 0, stream>>>(xb, wkvT, dots);
  make_M<<<dim3(32, 8), 256, 0, stream>>>(dots, w_out, Mbt);
  gemm2<<<ROWS / 128, 512, 0, stream>>>(qb, Mbt, b_out, out);
}

// Round 5
// 177.761 us; speedup vs baseline: 2.2256x; 1.1085x over previous
//
#include <hip/hip_runtime.h>
#include <hip/hip_bf16.h>
#include <stdint.h>

#define HEADS 8
#define DHEAD 64
#define BATCH 4
#define SEQ   8192
#define DIM   256
#define INNER 512
#define QKVC  1536
#define ROWS  32768   // BATCH*SEQ
#define EPS   1e-5f

typedef unsigned short u16;
typedef unsigned long long u64;
typedef __attribute__((ext_vector_type(8))) short bf16x8;
typedef __attribute__((ext_vector_type(4))) float f32x4;

#define AS1 __attribute__((address_space(1)))
#define AS3 __attribute__((address_space(3)))

__device__ __forceinline__ void async16(const void* g, void* l) {
  __builtin_amdgcn_global_load_lds((AS1 unsigned int*)g, (AS3 unsigned int*)l, 16, 0, 0);
}

__device__ __forceinline__ float bf2f(u16 u) {
  union { uint32_t i; float f; } v; v.i = ((uint32_t)u) << 16; return v.f;
}
__device__ __forceinline__ u16 f2bf(float f) {
  union { float f; uint32_t i; } v; v.f = f;
  uint32_t x = v.i;
  return (u16)((x + 0x7fffu + ((x >> 16) & 1u)) >> 16);  // RNE
}

// ---------------- prep: cvt_x + q-weights (row-major) + permuted kv-weights + zero dots ----
// blocks [0,8192): xb ; [8192,8704): wqB ; [8704,9728): wkvT ; [9728,9856): zero dots
__global__ __launch_bounds__(256) void prep(const float* __restrict__ x,
                                            const float* __restrict__ w,
                                            u16* __restrict__ xb,
                                            u16* __restrict__ wqB,
                                            u16* __restrict__ wkvT,
                                            float* __restrict__ dots) {
  int bid = blockIdx.x;
  if (bid < 8192) {
    int i = (bid * 256 + threadIdx.x) * 4;
    float4 v = *(const float4*)(x + i);
    ushort4 o; o.x = f2bf(v.x); o.y = f2bf(v.y); o.z = f2bf(v.z); o.w = f2bf(v.w);
    *(ushort4*)(xb + i) = o;
  } else if (bid < 8704) {
    int id = (bid - 8192) * 256 + threadIdx.x;  // 0..131071
    int k = id >> 9, j = id & 511;
    wqB[id] = f2bf(w[k * QKVC + j]);            // Wq row-major [256 k][512 j]
  } else if (bid < 9728) {
    int id = (bid - 8704) * 256 + threadIdx.x;  // 0..262143
    int k = id & 255;
    int r = (id >> 8) & 127;                    // 0..63=k-dim, 64..127=v-dim
    int h = id >> 15;                           // 0..7
    int oc = (r < 64) ? (512 + h * 64 + r) : (1024 + h * 64 + (r - 64));
    wkvT[id] = f2bf(w[k * QKVC + oc]);
  } else {
    int i = ((bid - 9728) * 256 + threadIdx.x) * 4;
    float4 z; z.x = 0.f; z.y = 0.f; z.z = 0.f; z.w = 0.f;
    *(float4*)(dots + i) = z;
  }
}

// ---------------- shared GEMM tile core (C = A @ Bt^T), 128x128 tile, BK=64, 256 thr ----
__device__ __forceinline__ void gemm_tile(const u16* __restrict__ A, int lda,
                                          const u16* __restrict__ Bt, int ldb,
                                          int K, int row0, int col0,
                                          u16* sA, u16* sB, f32x4 acc[4][4]) {
  const int tid = threadIdx.x, lane = tid & 63, wave = tid >> 6;
  const int mr = (wave >> 1) * 64, nc = (wave & 1) * 64;
  for (int kk = 0; kk < K; kk += 64) {
#pragma unroll
    for (int it = 0; it < 4; ++it) {
      int s = it * 256 + tid;
      int r = s >> 3, c = (s & 7) << 3;
      async16(A + (size_t)(row0 + r) * lda + kk + c, sA + (it * 256 + wave * 64) * 8);
      async16(Bt + (size_t)(col0 + r) * ldb + kk + c, sB + (it * 256 + wave * 64) * 8);
    }
    __syncthreads();
#pragma unroll
    for (int ks = 0; ks < 2; ++ks) {
      bf16x8 af[4], bfr[4];
#pragma unroll
      for (int f = 0; f < 4; ++f) {
        af[f]  = *(const bf16x8*)&sA[(mr + f * 16 + (lane & 15)) * 64 + ks * 32 + (lane >> 4) * 8];
        bfr[f] = *(const bf16x8*)&sB[(nc + f * 16 + (lane & 15)) * 64 + ks * 32 + (lane >> 4) * 8];
      }
#pragma unroll
      for (int fm = 0; fm < 4; ++fm)
#pragma unroll
        for (int fn = 0; fn < 4; ++fn)
          acc[fm][fn] = __builtin_amdgcn_mfma_f32_16x16x32_bf16(af[fm], bfr[fn], acc[fm][fn], 0, 0, 0);
    }
    __syncthreads();
  }
}

// ---------------- GEMM-KV + instance norm (register/shuffle) + dots ----------------
// grid (256 row-tiles, 8 heads), 256 thr. Each wave's MFMA quadrant = one half
// (k or v) x 64 tokens: row stats via 4-step shfl_xor butterfly over lane&15,
// normalized bf16 written straight to transposed knT/vnT (packed b64, 2-way
// bank alias = free). knT/vnT alias sA/sB -> LDS 34.8 KB -> 4 blocks/CU.
__global__ __launch_bounds__(256, 4) void gemm_kv_dots(const u16* __restrict__ A,
                                                       const u16* __restrict__ wkvT,
                                                       float* __restrict__ dots) {
  __shared__ alignas(16) u16 smem[17408];  // 34816 B
  u16* sA  = smem;
  u16* sB  = smem + 8192;
  u16* knT = smem;            // [64 d][136 tok-stride] — aliases sA/sB post K-loop
  u16* vnT = smem + 8704;

  const int tid = threadIdx.x, lane = tid & 63, wave = tid >> 6;
  const int m = lane & 15, q = lane >> 4;
  const int row0 = blockIdx.x * 128;
  const int h = blockIdx.y;
  const u16* Bt = wkvT + h * 128 * 256;
  const int half = wave & 1;              // 0 = k cols, 1 = v cols
  const int rowbase = (wave >> 1) * 64;   // local token base of this wave's quadrant

  f32x4 acc[4][4];
#pragma unroll
  for (int i = 0; i < 4; ++i)
#pragma unroll
    for (int j = 0; j < 4; ++j) acc[i][j] = (f32x4){0.f, 0.f, 0.f, 0.f};

  gemm_tile(A, DIM, Bt, DIM, DIM, row0, 0, sA, sB, acc);
  // gemm_tile ends with __syncthreads(): sA/sB reads complete -> safe to alias.

  u16* dst = half ? vnT : knT;
#pragma unroll
  for (int fm = 0; fm < 4; ++fm) {
    // per-lane partials over the 4 fn column-groups (4 rows in the f32x4)
    f32x4 s  = acc[fm][0] + acc[fm][1] + acc[fm][2] + acc[fm][3];
    f32x4 s2 = (f32x4){0.f, 0.f, 0.f, 0.f};
#pragma unroll
    for (int fn = 0; fn < 4; ++fn)
#pragma unroll
      for (int r = 0; r < 4; ++r) s2[r] = fmaf(acc[fm][fn][r], acc[fm][fn][r], s2[r]);
    // butterfly over lane&15 -> full 64-col row sums
#pragma unroll
    for (int mask = 1; mask <= 8; mask <<= 1) {
#pragma unroll
      for (int r = 0; r < 4; ++r) {
        s[r]  += __shfl_xor(s[r],  mask, 64);
        s2[r] += __shfl_xor(s2[r], mask, 64);
      }
    }
    f32x4 mu, rs;
#pragma unroll
    for (int r = 0; r < 4; ++r) {
      mu[r] = s[r] * (1.f / 64.f);
      float var = s2[r] * (1.f / 64.f) - mu[r] * mu[r];
      rs[r] = rsqrtf(var + EPS);
    }
    const int tokb = rowbase + fm * 16 + q * 4;
#pragma unroll
    for (int fn = 0; fn < 4; ++fn) {
      int d = fn * 16 + m;
      u64 pk = 0;
#pragma unroll
      for (int r = 0; r < 4; ++r) {
        u16 hv = f2bf((acc[fm][fn][r] - mu[r]) * rs[r]);
        pk |= (u64)hv << (16 * r);
      }
      *(u64*)(dst + d * 136 + tokb) = pk;   // 8B-aligned; 2-way bank alias (free)
    }
  }
  __syncthreads();

  // dots[d][e] += sum_tok knT[d][tok]*vnT[e][tok] via MFMA (K=128 tokens)
  f32x4 dacc[4];
#pragma unroll
  for (int f = 0; f < 4; ++f) dacc[f] = (f32x4){0.f, 0.f, 0.f, 0.f};
#pragma unroll
  for (int ks = 0; ks < 4; ++ks) {
    bf16x8 a = *(const bf16x8*)&knT[(wave * 16 + m) * 136 + ks * 32 + q * 8];
#pragma unroll
    for (int fn = 0; fn < 4; ++fn) {
      bf16x8 bb = *(const bf16x8*)&vnT[(fn * 16 + m) * 136 + ks * 32 + q * 8];
      dacc[fn] = __builtin_amdgcn_mfma_f32_16x16x32_bf16(a, bb, dacc[fn], 0, 0, 0);
    }
  }

  const int b = blockIdx.x >> 6;
  float* dbase = dots + (size_t)(b * 8 + h) * 4096;
#pragma unroll
  for (int fn = 0; fn < 4; ++fn) {
    int e = fn * 16 + m;
#pragma unroll
    for (int r = 0; r < 4; ++r) {
      int d = wave * 16 + q * 4 + r;
      atomicAdd(dbase + d * 64 + e, dacc[fn][r]);
    }
  }
}

// ---------------- fold dots into w_out ----------------
// Mbt[b][c][h*64+j] = sum_e dots[b,h,j,e]*w_out[h*64+e][c]/SEQ
__global__ __launch_bounds__(256) void make_M(const float* __restrict__ dots,
                                              const float* __restrict__ wout,
                                              u16* __restrict__ Mbt) {
  __shared__ float dl[8][64];
  const int bh = blockIdx.x, b = bh >> 3, h = bh & 7;
  const int jg = blockIdx.y;
  const int c = threadIdx.x;
  for (int i = threadIdx.x; i < 512; i += 256)
    ((float*)dl)[i] = dots[(size_t)bh * 4096 + jg * 512 + i];
  __syncthreads();
  float accv[8];
#pragma unroll
  for (int jj = 0; jj < 8; ++jj) accv[jj] = 0.f;
  for (int e = 0; e < 64; ++e) {
    float w = wout[(h * 64 + e) * DIM + c];
#pragma unroll
    for (int jj = 0; jj < 8; ++jj) accv[jj] = fmaf(dl[jj][e], w, accv[jj]);
  }
  const float inv_n = 1.0f / (float)SEQ;
  u16* outp = Mbt + ((size_t)(b * 256 + c)) * 512 + h * 64 + jg * 8;
#pragma unroll
  for (int jj = 0; jj < 8; ++jj) outp[jj] = f2bf(accv[jj] * inv_n);
}

// ---------------- make_G: Gt[b][c][k] = sum_j Mbt[b][c][j] * wqB[k][j] ----------------
// grid (2 c-tiles, 2 k-tiles, 4 batches). Folds q-projection into M: the big
// q GEMM + 33MB qb buffer vanish; final stage reads x directly.
__global__ __launch_bounds__(256) void make_G(const u16* __restrict__ Mbt,
                                              const u16* __restrict__ wqB,
                                              u16* __restrict__ Gt) {
  __shared__ alignas(16) u16 sA[128 * 64];
  __shared__ alignas(16) u16 sB[128 * 64];
  const int lane = threadIdx.x & 63, wave = threadIdx.x >> 6;
  const int row0 = blockIdx.x * 128, col0 = blockIdx.y * 128;
  const int b = blockIdx.z;
  f32x4 acc[4][4];
#pragma unroll
  for (int i = 0; i < 4; ++i)
#pragma unroll
    for (int j = 0; j < 4; ++j) acc[i][j] = (f32x4){0.f, 0.f, 0.f, 0.f};

  gemm_tile(Mbt + (size_t)b * 256 * 512, INNER, wqB, INNER, INNER, row0, col0, sA, sB, acc);

  u16* out = Gt + (size_t)b * 256 * 256;
  const int mr = (wave >> 1) * 64, nc = (wave & 1) * 64;
#pragma unroll
  for (int fm = 0; fm < 4; ++fm) {
    int rbase = row0 + mr + fm * 16 + (lane >> 4) * 4;
#pragma unroll
    for (int fn = 0; fn < 4; ++fn) {
      int col = col0 + nc + fn * 16 + (lane & 15);
#pragma unroll
      for (int r = 0; r < 4; ++r)
        out[(size_t)(rbase + r) * DIM + col] = f2bf(acc[fm][fn][r]);
    }
  }
}

// ---------------- gemm_out: out = x @ G[b] + bias ; [32768,256]@[256,256] fp32 out ----
__global__ __launch_bounds__(256) void gemm_out(const u16* __restrict__ A,
                                                const u16* __restrict__ Gt,
                                                const float* __restrict__ bias,
                                                float* __restrict__ out) {
  __shared__ alignas(16) u16 sA[128 * 64];
  __shared__ alignas(16) u16 sB[128 * 64];
  const int lane = threadIdx.x & 63, wave = threadIdx.x >> 6;
  const int row0 = blockIdx.x * 128, col0 = blockIdx.y * 128;
  const int b = blockIdx.x >> 6;
  const u16* Bt = Gt + (size_t)b * 256 * 256;   // [256 cols][256 k]
  f32x4 acc[4][4];
#pragma unroll
  for (int i = 0; i < 4; ++i)
#pragma unroll
    for (int j = 0; j < 4; ++j) acc[i][j] = (f32x4){0.f, 0.f, 0.f, 0.f};

  gemm_tile(A, DIM, Bt, DIM, DIM, row0, col0, sA, sB, acc);

  const int mr = (wave >> 1) * 64, nc = (wave & 1) * 64;
#pragma unroll
  for (int fm = 0; fm < 4; ++fm) {
    int rbase = row0 + mr + fm * 16 + (lane >> 4) * 4;
#pragma unroll
    for (int fn = 0; fn < 4; ++fn) {
      int col = col0 + nc + fn * 16 + (lane & 15);
      float bb = bias[col];
#pragma unroll
      for (int r = 0; r < 4; ++r)
        out[(size_t)(rbase + r) * DIM + col] = acc[fm][fn][r] + bb;
    }
  }
}

// ---------------- launch ----------------
extern "C" void kernel_launch(void* const* d_in, const int* in_sizes, int n_in,
                              void* d_out, int out_size, void* d_ws, size_t ws_size,
                              hipStream_t stream) {
  const float* x     = (const float*)d_in[0];
  const float* w_qkv = (const float*)d_in[1];
  const float* w_out = (const float*)d_in[2];
  const float* b_out = (const float*)d_in[3];
  float* out = (float*)d_out;

  char* ws = (char*)d_ws;
  size_t off = 0;
  u16* xb    = (u16*)(ws + off); off += (size_t)ROWS * DIM * 2;          // 16.78 MB
  u16* wqB   = (u16*)(ws + off); off += (size_t)DIM * INNER * 2;         // 0.26 MB
  u16* wkvT  = (u16*)(ws + off); off += (size_t)HEADS * 128 * DIM * 2;   // 0.52 MB
  float* dots = (float*)(ws + off); off += (size_t)32 * 64 * 64 * 4;     // 0.52 MB
  u16* Mbt   = (u16*)(ws + off); off += (size_t)BATCH * 256 * 512 * 2;   // 1.05 MB
  u16* Gt    = (u16*)(ws + off); off += (size_t)BATCH * 256 * 256 * 2;   // 0.52 MB

  prep<<<9856, 256, 0, stream>>>(x, w_qkv, xb, wqB, wkvT, dots);
  gemm_kv_dots<<<dim3(ROWS / 128, HEADS), 256, 0, stream>>>(xb, wkvT, dots);
  make_M<<<dim3(32, 8), 256, 0, stream>>>(dots, w_out, Mbt);
  make_G<<<dim3(2, 2, BATCH), 256, 0, stream>>>(Mbt, wqB, Gt);
  gemm_out<<<dim3(ROWS / 128, 2), 256, 0, stream>>>(xb, Gt, b_out, out);
}

// Round 7
// 174.246 us; speedup vs baseline: 2.2705x; 1.0202x over previous
//
#include <hip/hip_runtime.h>
#include <hip/hip_bf16.h>
#include <stdint.h>

#define HEADS 8
#define DHEAD 64
#define BATCH 4
#define SEQ   8192
#define DIM   256
#define INNER 512
#define QKVC  1536
#define ROWS  32768   // BATCH*SEQ
#define EPS   1e-5f

typedef unsigned short u16;
typedef unsigned long long u64;
typedef __attribute__((ext_vector_type(8))) short bf16x8;
typedef __attribute__((ext_vector_type(4))) float f32x4;

#define AS1 __attribute__((address_space(1)))
#define AS3 __attribute__((address_space(3)))

__device__ __forceinline__ void async16(const void* g, void* l) {
  __builtin_amdgcn_global_load_lds((AS1 unsigned int*)g, (AS3 unsigned int*)l, 16, 0, 0);
}

__device__ __forceinline__ float bf2f(u16 u) {
  union { uint32_t i; float f; } v; v.i = ((uint32_t)u) << 16; return v.f;
}
__device__ __forceinline__ u16 f2bf(float f) {
  union { float f; uint32_t i; } v; v.f = f;
  uint32_t x = v.i;
  return (u16)((x + 0x7fffu + ((x >> 16) & 1u)) >> 16);  // RNE
}

// ---------------- prep ----------------
// blocks [0,8192): xb ; [8192,8704): wqB ; [8704,9728): wkvP (MFMA-fragment-packed)
// [9728,9856): zero dots
// wkvP per head h (32768 u16): frag_id = ((kk*2+ks)*2+half)*4+fn  (64 frags);
//   elem(lane,j): kidx = kk*64+ks*32+(lane>>4)*8+j, col = half*64+fn*16+(lane&15),
//   oc = col<64 ? 512+h*64+col : 1024+h*64+(col-64); value = w[kidx][oc].
// id bit-slice: j(3) | lane(6) | frag(6) | h(3)  — R6 bug was frag&31 / h=id>>14.
__global__ __launch_bounds__(256) void prep(const float* __restrict__ x,
                                            const float* __restrict__ w,
                                            u16* __restrict__ xb,
                                            u16* __restrict__ wqB,
                                            u16* __restrict__ wkvP,
                                            float* __restrict__ dots) {
  int bid = blockIdx.x;
  if (bid < 8192) {
    int i = (bid * 256 + threadIdx.x) * 4;
    float4 v = *(const float4*)(x + i);
    ushort4 o; o.x = f2bf(v.x); o.y = f2bf(v.y); o.z = f2bf(v.z); o.w = f2bf(v.w);
    *(ushort4*)(xb + i) = o;
  } else if (bid < 8704) {
    int id = (bid - 8192) * 256 + threadIdx.x;  // 0..131071
    int k = id >> 9, j = id & 511;
    wqB[id] = f2bf(w[k * QKVC + j]);            // Wq row-major [256 k][512 j]
  } else if (bid < 9728) {
    int id = (bid - 8704) * 256 + threadIdx.x;  // 0..262143
    int j    = id & 7;
    int lane = (id >> 3) & 63;
    int frag = (id >> 9) & 63;                  // 6 bits: 64 fragments
    int h    = id >> 15;                        // 3 bits: 8 heads
    int fn   = frag & 3;
    int half = (frag >> 2) & 1;
    int ks   = (frag >> 3) & 1;
    int kk   = frag >> 4;
    int col  = half * 64 + fn * 16 + (lane & 15);
    int kidx = kk * 64 + ks * 32 + (lane >> 4) * 8 + j;
    int oc   = (col < 64) ? (512 + h * 64 + col) : (1024 + h * 64 + (col - 64));
    wkvP[id] = f2bf(w[kidx * QKVC + oc]);
  } else {
    int i = ((bid - 9728) * 256 + threadIdx.x) * 4;
    float4 z; z.x = 0.f; z.y = 0.f; z.z = 0.f; z.w = 0.f;
    *(float4*)(dots + i) = z;
  }
}

// ---------------- shared GEMM tile core (C = A @ Bt^T), 128x128 tile, BK=64, 256 thr ----
// XOR-swizzled LDS: chunk c holds global chunk (row=c>>3, kc=(c^r)&7) ->
// b128 frag reads are bank-conflict-free; staging stays 128B-coalesced.
__device__ __forceinline__ void gemm_tile(const u16* __restrict__ A, int lda,
                                          const u16* __restrict__ Bt, int ldb,
                                          int K, int row0, int col0,
                                          u16* sA, u16* sB, f32x4 acc[4][4]) {
  const int tid = threadIdx.x, lane = tid & 63, wave = tid >> 6;
  const int m = lane & 15, q = lane >> 4;
  const int mr = (wave >> 1) * 64, nc = (wave & 1) * 64;
  for (int kk = 0; kk < K; kk += 64) {
#pragma unroll
    for (int it = 0; it < 4; ++it) {
      int c = it * 256 + tid;
      int r = c >> 3, kc = (c ^ r) & 7;
      async16(A + (size_t)(row0 + r) * lda + kk + kc * 8, sA + (it * 256 + wave * 64) * 8);
      async16(Bt + (size_t)(col0 + r) * ldb + kk + kc * 8, sB + (it * 256 + wave * 64) * 8);
    }
    __syncthreads();
#pragma unroll
    for (int ks = 0; ks < 2; ++ks) {
      bf16x8 af[4], bfr[4];
#pragma unroll
      for (int f = 0; f < 4; ++f) {
        int ra = mr + f * 16 + m;
        int rb = nc + f * 16 + m;
        af[f]  = *(const bf16x8*)&sA[ra * 64 + (((ks * 4 + q) ^ (m & 7)) * 8)];
        bfr[f] = *(const bf16x8*)&sB[rb * 64 + (((ks * 4 + q) ^ (m & 7)) * 8)];
      }
#pragma unroll
      for (int fm = 0; fm < 4; ++fm)
#pragma unroll
        for (int fn = 0; fn < 4; ++fn)
          acc[fm][fn] = __builtin_amdgcn_mfma_f32_16x16x32_bf16(af[fm], bfr[fn], acc[fm][fn], 0, 0, 0);
    }
    __syncthreads();
  }
}

// ---------------- GEMM-KV + instance norm (register/shuffle) + dots ----------------
// grid (256 row-tiles, 8 heads), 256 thr. B fragments loaded from prepacked
// global (L2-hot) straight into VGPRs — no sB LDS at all. sA XOR-swizzled.
__global__ __launch_bounds__(256, 3) void gemm_kv_dots(const u16* __restrict__ A,
                                                       const u16* __restrict__ wkvP,
                                                       float* __restrict__ dots) {
  __shared__ alignas(16) u16 smem[17408];  // 34816 B
  u16* sA  = smem;            // [128 rows][64] swizzled, K-loop only
  u16* knT = smem;            // [64 d][136 tok] — aliases sA post K-loop
  u16* vnT = smem + 8704;

  const int tid = threadIdx.x, lane = tid & 63, wave = tid >> 6;
  const int m = lane & 15, q = lane >> 4;
  const int row0 = blockIdx.x * 128;
  const int h = blockIdx.y;
  const int half = wave & 1;              // 0 = k cols, 1 = v cols
  const int rowbase = (wave >> 1) * 64;   // local token base of this wave's quadrant
  const u16* bp = wkvP + (size_t)h * 32768 + lane * 8;

  f32x4 acc[4][4];
#pragma unroll
  for (int i = 0; i < 4; ++i)
#pragma unroll
    for (int j = 0; j < 4; ++j) acc[i][j] = (f32x4){0.f, 0.f, 0.f, 0.f};

#pragma unroll
  for (int kk = 0; kk < 4; ++kk) {
    // B fragments: coalesced 16B global loads, drained by the same barrier
    bf16x8 breg[2][4];
#pragma unroll
    for (int ks = 0; ks < 2; ++ks)
#pragma unroll
      for (int fn = 0; fn < 4; ++fn)
        breg[ks][fn] = *(const bf16x8*)(bp + (size_t)((((kk * 2 + ks) * 2 + half) * 4 + fn) * 512));
    // stage sA (swizzled)
#pragma unroll
    for (int it = 0; it < 4; ++it) {
      int c = it * 256 + tid;
      int r = c >> 3, kc = (c ^ r) & 7;
      async16(A + (size_t)(row0 + r) * DIM + kk * 64 + kc * 8, sA + (it * 256 + wave * 64) * 8);
    }
    __syncthreads();
#pragma unroll
    for (int ks = 0; ks < 2; ++ks) {
      bf16x8 af[4];
#pragma unroll
      for (int f = 0; f < 4; ++f) {
        int r = rowbase + f * 16 + m;
        af[f] = *(const bf16x8*)&sA[r * 64 + (((ks * 4 + q) ^ (m & 7)) * 8)];
      }
#pragma unroll
      for (int fm = 0; fm < 4; ++fm)
#pragma unroll
        for (int fn = 0; fn < 4; ++fn)
          acc[fm][fn] = __builtin_amdgcn_mfma_f32_16x16x32_bf16(af[fm], breg[ks][fn], acc[fm][fn], 0, 0, 0);
    }
    __syncthreads();
  }

  // epilogue: row stats via shfl butterfly over lane&15, write transposed bf16
  u16* dst = half ? vnT : knT;
#pragma unroll
  for (int fm = 0; fm < 4; ++fm) {
    f32x4 s  = acc[fm][0] + acc[fm][1] + acc[fm][2] + acc[fm][3];
    f32x4 s2 = (f32x4){0.f, 0.f, 0.f, 0.f};
#pragma unroll
    for (int fn = 0; fn < 4; ++fn)
#pragma unroll
      for (int r = 0; r < 4; ++r) s2[r] = fmaf(acc[fm][fn][r], acc[fm][fn][r], s2[r]);
#pragma unroll
    for (int mask = 1; mask <= 8; mask <<= 1) {
#pragma unroll
      for (int r = 0; r < 4; ++r) {
        s[r]  += __shfl_xor(s[r],  mask, 64);
        s2[r] += __shfl_xor(s2[r], mask, 64);
      }
    }
    f32x4 mu, rs;
#pragma unroll
    for (int r = 0; r < 4; ++r) {
      mu[r] = s[r] * (1.f / 64.f);
      float var = s2[r] * (1.f / 64.f) - mu[r] * mu[r];
      rs[r] = rsqrtf(var + EPS);
    }
    const int tokb = rowbase + fm * 16 + q * 4;
#pragma unroll
    for (int fn = 0; fn < 4; ++fn) {
      int d = fn * 16 + m;
      u64 pk = 0;
#pragma unroll
      for (int r = 0; r < 4; ++r) {
        u16 hv = f2bf((acc[fm][fn][r] - mu[r]) * rs[r]);
        pk |= (u64)hv << (16 * r);
      }
      *(u64*)(dst + d * 136 + tokb) = pk;   // 8B-aligned; 2-way bank alias (free)
    }
  }
  __syncthreads();

  // dots[d][e] += sum_tok knT[d][tok]*vnT[e][tok] via MFMA (K=128 tokens)
  f32x4 dacc[4];
#pragma unroll
  for (int f = 0; f < 4; ++f) dacc[f] = (f32x4){0.f, 0.f, 0.f, 0.f};
#pragma unroll
  for (int ks = 0; ks < 4; ++ks) {
    bf16x8 a = *(const bf16x8*)&knT[(wave * 16 + m) * 136 + ks * 32 + q * 8];
#pragma unroll
    for (int fn = 0; fn < 4; ++fn) {
      bf16x8 bb = *(const bf16x8*)&vnT[(fn * 16 + m) * 136 + ks * 32 + q * 8];
      dacc[fn] = __builtin_amdgcn_mfma_f32_16x16x32_bf16(a, bb, dacc[fn], 0, 0, 0);
    }
  }

  const int b = blockIdx.x >> 6;
  float* dbase = dots + (size_t)(b * 8 + h) * 4096;
#pragma unroll
  for (int fn = 0; fn < 4; ++fn) {
    int e = fn * 16 + m;
#pragma unroll
    for (int r = 0; r < 4; ++r) {
      int d = wave * 16 + q * 4 + r;
      atomicAdd(dbase + d * 64 + e, dacc[fn][r]);
    }
  }
}

// ---------------- fold dots into w_out ----------------
// Mbt[b][c][h*64+j] = sum_e dots[b,h,j,e]*w_out[h*64+e][c]/SEQ
__global__ __launch_bounds__(256) void make_M(const float* __restrict__ dots,
                                              const float* __restrict__ wout,
                                              u16* __restrict__ Mbt) {
  __shared__ float dl[8][64];
  const int bh = blockIdx.x, b = bh >> 3, h = bh & 7;
  const int jg = blockIdx.y;
  const int c = threadIdx.x;
  for (int i = threadIdx.x; i < 512; i += 256)
    ((float*)dl)[i] = dots[(size_t)bh * 4096 + jg * 512 + i];
  __syncthreads();
  float accv[8];
#pragma unroll
  for (int jj = 0; jj < 8; ++jj) accv[jj] = 0.f;
  for (int e = 0; e < 64; ++e) {
    float w = wout[(h * 64 + e) * DIM + c];
#pragma unroll
    for (int jj = 0; jj < 8; ++jj) accv[jj] = fmaf(dl[jj][e], w, accv[jj]);
  }
  const float inv_n = 1.0f / (float)SEQ;
  u16* outp = Mbt + ((size_t)(b * 256 + c)) * 512 + h * 64 + jg * 8;
#pragma unroll
  for (int jj = 0; jj < 8; ++jj) outp[jj] = f2bf(accv[jj] * inv_n);
}

// ---------------- make_G: Gt[b][c][k] = sum_j Mbt[b][c][j] * wqB[k][j] ----------------
__global__ __launch_bounds__(256) void make_G(const u16* __restrict__ Mbt,
                                              const u16* __restrict__ wqB,
                                              u16* __restrict__ Gt) {
  __shared__ alignas(16) u16 sA[128 * 64];
  __shared__ alignas(16) u16 sB[128 * 64];
  const int lane = threadIdx.x & 63, wave = threadIdx.x >> 6;
  const int row0 = blockIdx.x * 128, col0 = blockIdx.y * 128;
  const int b = blockIdx.z;
  f32x4 acc[4][4];
#pragma unroll
  for (int i = 0; i < 4; ++i)
#pragma unroll
    for (int j = 0; j < 4; ++j) acc[i][j] = (f32x4){0.f, 0.f, 0.f, 0.f};

  gemm_tile(Mbt + (size_t)b * 256 * 512, INNER, wqB, INNER, INNER, row0, col0, sA, sB, acc);

  u16* out = Gt + (size_t)b * 256 * 256;
  const int mr = (wave >> 1) * 64, nc = (wave & 1) * 64;
#pragma unroll
  for (int fm = 0; fm < 4; ++fm) {
    int rbase = row0 + mr + fm * 16 + (lane >> 4) * 4;
#pragma unroll
    for (int fn = 0; fn < 4; ++fn) {
      int col = col0 + nc + fn * 16 + (lane & 15);
#pragma unroll
      for (int r = 0; r < 4; ++r)
        out[(size_t)(rbase + r) * DIM + col] = f2bf(acc[fm][fn][r]);
    }
  }
}

// ---------------- gemm_out: out = x @ G[b] + bias ; [32768,256]@[256,256] fp32 out ----
__global__ __launch_bounds__(256) void gemm_out(const u16* __restrict__ A,
                                                const u16* __restrict__ Gt,
                                                const float* __restrict__ bias,
                                                float* __restrict__ out) {
  __shared__ alignas(16) u16 sA[128 * 64];
  __shared__ alignas(16) u16 sB[128 * 64];
  const int lane = threadIdx.x & 63, wave = threadIdx.x >> 6;
  const int row0 = blockIdx.x * 128, col0 = blockIdx.y * 128;
  const int b = blockIdx.x >> 6;
  const u16* Bt = Gt + (size_t)b * 256 * 256;   // [256 cols][256 k]
  f32x4 acc[4][4];
#pragma unroll
  for (int i = 0; i < 4; ++i)
#pragma unroll
    for (int j = 0; j < 4; ++j) acc[i][j] = (f32x4){0.f, 0.f, 0.f, 0.f};

  gemm_tile(A, DIM, Bt, DIM, DIM, row0, col0, sA, sB, acc);

  const int mr = (wave >> 1) * 64, nc = (wave & 1) * 64;
#pragma unroll
  for (int fm = 0; fm < 4; ++fm) {
    int rbase = row0 + mr + fm * 16 + (lane >> 4) * 4;
#pragma unroll
    for (int fn = 0; fn < 4; ++fn) {
      int col = col0 + nc + fn * 16 + (lane & 15);
      float bb = bias[col];
#pragma unroll
      for (int r = 0; r < 4; ++r)
        out[(size_t)(rbase + r) * DIM + col] = acc[fm][fn][r] + bb;
    }
  }
}

// ---------------- launch ----------------
extern "C" void kernel_launch(void* const* d_in, const int* in_sizes, int n_in,
                              void* d_out, int out_size, void* d_ws, size_t ws_size,
                              hipStream_t stream) {
  const float* x     = (const float*)d_in[0];
  const float* w_qkv = (const float*)d_in[1];
  const float* w_out = (const float*)d_in[2];
  const float* b_out = (const float*)d_in[3];
  float* out = (float*)d_out;

  char* ws = (char*)d_ws;
  size_t off = 0;
  u16* xb    = (u16*)(ws + off); off += (size_t)ROWS * DIM * 2;          // 16.78 MB
  u16* wqB   = (u16*)(ws + off); off += (size_t)DIM * INNER * 2;         // 0.26 MB
  u16* wkvP  = (u16*)(ws + off); off += (size_t)HEADS * 128 * DIM * 2;   // 0.52 MB
  float* dots = (float*)(ws + off); off += (size_t)32 * 64 * 64 * 4;     // 0.52 MB
  u16* Mbt   = (u16*)(ws + off); off += (size_t)BATCH * 256 * 512 * 2;   // 1.05 MB
  u16* Gt    = (u16*)(ws + off); off += (size_t)BATCH * 256 * 256 * 2;   // 0.52 MB

  prep<<<9856, 256, 0, stream>>>(x, w_qkv, xb, wqB, wkvP, dots);
  gemm_kv_dots<<<dim3(ROWS / 128, HEADS), 256, 0, stream>>>(xb, wkvP, dots);
  make_M<<<dim3(32, 8), 256, 0, stream>>>(dots, w_out, Mbt);
  make_G<<<dim3(2, 2, BATCH), 256, 0, stream>>>(Mbt, wqB, Gt);
  gemm_out<<<dim3(ROWS / 128, 2), 256, 0, stream>>>(xb, Gt, b_out, out);
}